// Round 4
// baseline (205.508 us; speedup 1.0000x reference)
//
#include <hip/hip_runtime.h>
#include <math.h>

#define B_   8
#define N_   512
#define F_   64
#define G_   64
#define M_   4
#define E_   4
#define MEG  1024
#define NEG_ -9e15f

typedef __attribute__((ext_vector_type(8))) __bf16 bf16x8;
typedef __attribute__((ext_vector_type(4))) float f32x4;
typedef unsigned short ush;

static __device__ __forceinline__ float leaky01(float x) { return x > 0.f ? x : 0.01f * x; }
static __device__ __forceinline__ ush bfu(float x) { __bf16 h = (__bf16)x; return __builtin_bit_cast(ush, h); }
static __device__ __forceinline__ bf16x8 asbf(int4 v) { return __builtin_bit_cast(bf16x8, v); }

// ---------------- kprep: all bf16 conversions / transposes / c-vectors ----------------
__global__ void __launch_bounds__(256) kprep(const float* __restrict__ X, const float* __restrict__ Ws,
                                             const float* __restrict__ a1, const float* __restrict__ a2,
                                             const float* __restrict__ W_emb1, const float* __restrict__ W2a,
                                             const float* __restrict__ W2b,
                                             ush* __restrict__ Xb, ush* __restrict__ WsT, ush* __restrict__ cpack,
                                             ush* __restrict__ W1b, ush* __restrict__ W2ab, ush* __restrict__ W2bb) {
  int idx = blockIdx.x * 256 + threadIdx.x;
  if (idx < 65536) {                       // Xb [4096][64] bf16
    float4 v = ((const float4*)X)[idx];
    ushort4 o; o.x = bfu(v.x); o.y = bfu(v.y); o.z = bfu(v.z); o.w = bfu(v.w);
    ((ushort4*)Xb)[idx] = o;
  } else if (idx < 131072) {               // WsT [em][g][f] bf16
    int j = idx - 65536; int em = j >> 12, g = (j >> 6) & 63, f = j & 63;
    WsT[j] = bfu(Ws[em * 4096 + f * 64 + g]);
  } else if (idx < 132096) {               // cpack [em][16][f]: rows 0,1 = Ws@a1, Ws@a2; rows 2..15 zero
    int j = idx - 131072; int em = j >> 6, f = j & 63;
    const float* wp = Ws + em * 4096 + f * 64;
    const float* p1 = a1 + em * 64; const float* p2 = a2 + em * 64;
    float c1 = 0.f, c2 = 0.f;
    for (int g = 0; g < 64; ++g) { float w = wp[g]; c1 = fmaf(w, p1[g], c1); c2 = fmaf(w, p2[g], c2); }
    cpack[em * 1024 + f] = bfu(c1);
    cpack[em * 1024 + 64 + f] = bfu(c2);
    for (int r = 2; r < 16; ++r) cpack[em * 1024 + r * 64 + f] = 0;
  } else if (idx < 148480) {               // W1b = bf16(W_emb1) [64][1024]
    int j = idx - 132096;
    float4 v = ((const float4*)W_emb1)[j];
    ushort4 o; o.x = bfu(v.x); o.y = bfu(v.y); o.z = bfu(v.z); o.w = bfu(v.w);
    ((ushort4*)W1b)[j] = o;
  } else if (idx < 152576) {               // W2ab = bf16(W2a) [256][64]
    int j = idx - 148480;
    float4 v = ((const float4*)W2a)[j];
    ushort4 o; o.x = bfu(v.x); o.y = bfu(v.y); o.z = bfu(v.z); o.w = bfu(v.w);
    ((ushort4*)W2ab)[j] = o;
  } else if (idx < 156672) {               // W2bb = bf16(W2b) [64][256]
    int j = idx - 152576;
    float4 v = ((const float4*)W2b)[j];
    ushort4 o; o.x = bfu(v.x); o.y = bfu(v.y); o.z = bfu(v.z); o.w = bfu(v.w);
    ((ushort4*)W2bb)[j] = o;
  }
}

// ---------------- K1: MFMA  WhT[bem][g][n] = (Ws^T · X^T);  s1/s2 via cpack MFMA ----------------
__global__ void __launch_bounds__(256) k1_wh(const ush* __restrict__ Xb, const ush* __restrict__ WsT,
                                             const ush* __restrict__ cpack,
                                             ush* __restrict__ WhT, float* __restrict__ s1,
                                             float* __restrict__ s2) {
  const int tid = threadIdx.x, lane = tid & 63, w = tid >> 6, c = lane & 15, grp = lane >> 4;
  const int blk = blockIdx.x, nt = blk & 7, em = (blk >> 3) & 15, b = blk >> 7;
  const int n0 = nt * 64, bem = b * 16 + em;
  f32x4 acc[4] = {};
  const ush* wsrow = WsT + em * 4096 + (w * 16 + c) * 64;
#pragma unroll
  for (int kk = 0; kk < 2; ++kk) {
    bf16x8 af = asbf(*(const int4*)(wsrow + kk * 32 + grp * 8));
#pragma unroll
    for (int t = 0; t < 4; ++t) {
      bf16x8 bv = asbf(*(const int4*)(Xb + (b * 512 + n0 + t * 16 + c) * 64 + kk * 32 + grp * 8));
      acc[t] = __builtin_amdgcn_mfma_f32_16x16x32_bf16(af, bv, acc[t], 0, 0, 0);
    }
  }
  ush* wout = WhT + bem * 32768;
#pragma unroll
  for (int t = 0; t < 4; ++t)
#pragma unroll
    for (int r = 0; r < 4; ++r)
      wout[(w * 16 + grp * 4 + r) * 512 + n0 + t * 16 + c] = bfu(acc[t][r]);
  if (w == 0) {                            // s1/s2: rows 0,1 of cpack·X^T
    f32x4 sacc[4] = {};
    const ush* crow = cpack + em * 1024 + c * 64;
#pragma unroll
    for (int kk = 0; kk < 2; ++kk) {
      bf16x8 af = asbf(*(const int4*)(crow + kk * 32 + grp * 8));
#pragma unroll
      for (int t = 0; t < 4; ++t) {
        bf16x8 bv = asbf(*(const int4*)(Xb + (b * 512 + n0 + t * 16 + c) * 64 + kk * 32 + grp * 8));
        sacc[t] = __builtin_amdgcn_mfma_f32_16x16x32_bf16(af, bv, sacc[t], 0, 0, 0);
      }
    }
    if (grp == 0) {
#pragma unroll
      for (int t = 0; t < 4; ++t) {
        s1[bem * 512 + n0 + t * 16 + c] = sacc[t][0];   // D row 0
        s2[bem * 512 + n0 + t * 16 + c] = sacc[t][1];   // D row 1
      }
    }
  }
}

// ---------------- K2: masked softmax + MFMA PV + ELU -> Hmid bf16 ----------------
__global__ void __launch_bounds__(256) k2_attn(const int* __restrict__ A,
                                               const ush* __restrict__ WhT,
                                               const float* __restrict__ s1,
                                               const float* __restrict__ s2,
                                               ush* __restrict__ Hb) {
  const int tid = threadIdx.x, lane = tid & 63, m = tid >> 6;
  const int grp = lane >> 4, col = lane & 15;
  const int blk = blockIdx.x;
  const int itile = blk & 31, e = (blk >> 5) & 3, b = blk >> 7;
  const int i0 = itile * 16;

  __shared__ unsigned maskw[16][17];
  __shared__ float sums_l[4][16];

  {
    const int row = tid >> 4, c = tid & 15;
    const int* ap = A + (((b * E_ + e) * N_) + i0 + row) * N_ + c * 32;
    unsigned wbits = 0;
#pragma unroll
    for (int k = 0; k < 32; k += 4) {
      int4 v = *(const int4*)(ap + k);
      wbits |= (v.x > 0 ? 1u : 0u) << k;
      wbits |= (v.y > 0 ? 1u : 0u) << (k + 1);
      wbits |= (v.z > 0 ? 1u : 0u) << (k + 2);
      wbits |= (v.w > 0 ? 1u : 0u) << (k + 3);
    }
    maskw[row][c] = wbits;
  }
  __syncthreads();

  const int bem = (b * E_ + e) * M_ + m;
  const float* s2p = s2 + bem * N_;
  const float s1row = s1[bem * N_ + i0 + col];

  float m2 = -INFINITY;
#pragma unroll
  for (int s = 0; s < 16; ++s) {
    unsigned mb = maskw[col][s] >> (grp * 8);
    const float* sp = s2p + s * 32 + grp * 8;
    float4 va = *(const float4*)sp;
    float4 vb = *(const float4*)(sp + 4);
    float sv[8] = {va.x, va.y, va.z, va.w, vb.x, vb.y, vb.z, vb.w};
#pragma unroll
    for (int i = 0; i < 8; ++i)
      m2 = fmaxf(m2, ((mb >> i) & 1u) ? sv[i] : -INFINITY);
  }
  m2 = fmaxf(m2, __shfl_xor(m2, 16));
  m2 = fmaxf(m2, __shfl_xor(m2, 32));
  const float mx = leaky01(s1row + m2);

  const ush* whp = WhT + bem * (G_ * N_) + col * N_ + grp * 8;
  f32x4 acc0 = {0.f, 0.f, 0.f, 0.f};
  f32x4 acc1 = acc0, acc2 = acc0, acc3 = acc0;
  float rsum = 0.f;
#pragma unroll
  for (int s = 0; s < 16; ++s) {
    unsigned mb = maskw[col][s] >> (grp * 8);
    const float* sp = s2p + s * 32 + grp * 8;
    float4 va = *(const float4*)sp;
    float4 vb = *(const float4*)(sp + 4);
    float sv[8] = {va.x, va.y, va.z, va.w, vb.x, vb.y, vb.z, vb.w};
    bf16x8 af;
#pragma unroll
    for (int i = 0; i < 8; ++i) {
      float pe = __expf(leaky01(s1row + sv[i]) - mx);
      float pi = ((mb >> i) & 1u) ? pe : 0.f;
      rsum += pi;
      af[i] = (__bf16)pi;
    }
    const int off = s * 32;
    int4 r0 = *(const int4*)(whp + off);
    int4 r1 = *(const int4*)(whp + 8192 + off);
    int4 r2 = *(const int4*)(whp + 16384 + off);
    int4 r3 = *(const int4*)(whp + 24576 + off);
    acc0 = __builtin_amdgcn_mfma_f32_16x16x32_bf16(af, asbf(r0), acc0, 0, 0, 0);
    acc1 = __builtin_amdgcn_mfma_f32_16x16x32_bf16(af, asbf(r1), acc1, 0, 0, 0);
    acc2 = __builtin_amdgcn_mfma_f32_16x16x32_bf16(af, asbf(r2), acc2, 0, 0, 0);
    acc3 = __builtin_amdgcn_mfma_f32_16x16x32_bf16(af, asbf(r3), acc3, 0, 0, 0);
  }
  rsum += __shfl_xor(rsum, 16);
  rsum += __shfl_xor(rsum, 32);
  if (grp == 0) sums_l[m][col] = rsum;
  __syncthreads();

  ush* op = Hb + (b * N_ + i0 + grp * 4) * MEG + m * 256 + e * 64 + col;
#pragma unroll
  for (int r = 0; r < 4; ++r) {
    float sv2 = sums_l[m][grp * 4 + r];
    float inv = sv2 > 0.f ? 1.f / sv2 : 0.f;
    float v0 = acc0[r] * inv; v0 = v0 > 0.f ? v0 : expm1f(v0);
    float v1 = acc1[r] * inv; v1 = v1 > 0.f ? v1 : expm1f(v1);
    float v2 = acc2[r] * inv; v2 = v2 > 0.f ? v2 : expm1f(v2);
    float v3 = acc3[r] * inv; v3 = v3 > 0.f ? v3 : expm1f(v3);
    op[r * MEG + 0]  = bfu(v0);
    op[r * MEG + 16] = bfu(v1);
    op[r * MEG + 32] = bfu(v2);
    op[r * MEG + 48] = bfu(v3);
  }
}

// ---------------- K3: MFMA  R = 0.5*(Hb @ W1b^T) + 0.5*X; per-block col partials ----------------
__global__ void __launch_bounds__(256) k3_emb(const ush* __restrict__ Hb, const ush* __restrict__ W1b,
                                              const float* __restrict__ X, float* __restrict__ R,
                                              float* __restrict__ PartR) {
  const int tid = threadIdx.x, lane = tid & 63, w = tid >> 6, c = lane & 15, grp = lane >> 4;
  const int r0 = blockIdx.x * 16;
  const ush* ha = Hb + (r0 + c) * 1024 + grp * 8;
  const ush* wb = W1b + (w * 16 + c) * 1024 + grp * 8;
  f32x4 acc = {};
#pragma unroll 8
  for (int kk = 0; kk < 32; ++kk) {
    bf16x8 af = asbf(*(const int4*)(ha + kk * 32));
    bf16x8 bv = asbf(*(const int4*)(wb + kk * 32));
    acc = __builtin_amdgcn_mfma_f32_16x16x32_bf16(af, bv, acc, 0, 0, 0);
  }
  const int col = w * 16 + c;
  float s = 0.f, q = 0.f;
#pragma unroll
  for (int r = 0; r < 4; ++r) {
    int row = r0 + grp * 4 + r;
    float v = 0.5f * acc[r] + 0.5f * X[row * 64 + col];
    R[row * 64 + col] = v;
    s += v; q = fmaf(v, v, q);
  }
  s += __shfl_xor(s, 16); s += __shfl_xor(s, 32);
  q += __shfl_xor(q, 16); q += __shfl_xor(q, 32);
  if (grp == 0) { PartR[blockIdx.x * 128 + col] = s; PartR[blockIdx.x * 128 + 64 + col] = q; }
}

// ---------------- kstat: Part[256][2][C] -> mu[C], rstd[C] ----------------
__global__ void __launch_bounds__(256) kstat(const float* __restrict__ Part, float* __restrict__ mu,
                                             float* __restrict__ rs, int C) {
  __shared__ float ls[256], lq[256];
  const int t = threadIdx.x;
  const int cc = (t & 127) + blockIdx.x * 128;
  const int q = t >> 7;
  float s = 0.f, qq = 0.f;
  if (cc < C) {
    for (int bk = q * 128; bk < q * 128 + 128; ++bk) {
      s += Part[bk * 2 * C + cc];
      qq += Part[bk * 2 * C + C + cc];
    }
  }
  ls[t] = s; lq[t] = qq;
  __syncthreads();
  if (t < 128 && cc < C) {
    float S = ls[t] + ls[t + 128], Q = lq[t] + lq[t + 128];
    float m = S * (1.f / 4096.f);
    float v = Q * (1.f / 4096.f) - m * m;
    mu[cc] = m; rs[cc] = rsqrtf(v + 1e-5f);
  }
}

// ---------------- K4: MFMA  T = BN(R) @ W2a^T ----------------
__global__ void __launch_bounds__(256) k4_node1(const float* __restrict__ R, const float* __restrict__ muR,
                                                const float* __restrict__ rsR, const ush* __restrict__ W2ab,
                                                float* __restrict__ T, float* __restrict__ PartT) {
  const int tid = threadIdx.x, lane = tid & 63, w = tid >> 6, c = lane & 15, grp = lane >> 4;
  const int r0 = blockIdx.x * 16, cb = w * 64;
  f32x4 acc[4] = {};
#pragma unroll
  for (int kk = 0; kk < 2; ++kk) {
    const float* rp = R + (r0 + c) * 64 + kk * 32 + grp * 8;
    float4 v0 = *(const float4*)rp;
    float4 v1 = *(const float4*)(rp + 4);
    float vv[8] = {v0.x, v0.y, v0.z, v0.w, v1.x, v1.y, v1.z, v1.w};
    bf16x8 af;
#pragma unroll
    for (int i = 0; i < 8; ++i) {
      int f = kk * 32 + grp * 8 + i;
      af[i] = (__bf16)((vv[i] - muR[f]) * rsR[f]);
    }
#pragma unroll
    for (int ct = 0; ct < 4; ++ct) {
      bf16x8 bv = asbf(*(const int4*)(W2ab + (cb + ct * 16 + c) * 64 + kk * 32 + grp * 8));
      acc[ct] = __builtin_amdgcn_mfma_f32_16x16x32_bf16(af, bv, acc[ct], 0, 0, 0);
    }
  }
#pragma unroll
  for (int ct = 0; ct < 4; ++ct) {
    float s = 0.f, q = 0.f;
#pragma unroll
    for (int r = 0; r < 4; ++r) {
      float v = acc[ct][r];
      T[(r0 + grp * 4 + r) * 256 + cb + ct * 16 + c] = v;
      s += v; q = fmaf(v, v, q);
    }
    s += __shfl_xor(s, 16); s += __shfl_xor(s, 32);
    q += __shfl_xor(q, 16); q += __shfl_xor(q, 32);
    if (grp == 0) {
      PartT[blockIdx.x * 512 + cb + ct * 16 + c] = s;
      PartT[blockIdx.x * 512 + 256 + cb + ct * 16 + c] = q;
    }
  }
}

// ---------------- K5: MFMA  S = BN_R(R) + ELU(BN(T)) @ W2b^T ----------------
__global__ void __launch_bounds__(256) k5_node2(const float* __restrict__ T, const float* __restrict__ muT,
                                                const float* __restrict__ rsT, const ush* __restrict__ W2bb,
                                                const float* __restrict__ R, const float* __restrict__ muR,
                                                const float* __restrict__ rsR,
                                                float* __restrict__ S, float* __restrict__ PartS) {
  const int tid = threadIdx.x, lane = tid & 63, w = tid >> 6, c = lane & 15, grp = lane >> 4;
  const int r0 = blockIdx.x * 16;
  f32x4 acc = {};
  const ush* wrow = W2bb + (w * 16 + c) * 256 + grp * 8;
  const float* trow = T + (r0 + c) * 256 + grp * 8;
#pragma unroll
  for (int kk = 0; kk < 8; ++kk) {
    float4 v0 = *(const float4*)(trow + kk * 32);
    float4 v1 = *(const float4*)(trow + kk * 32 + 4);
    float vv[8] = {v0.x, v0.y, v0.z, v0.w, v1.x, v1.y, v1.z, v1.w};
    bf16x8 af;
#pragma unroll
    for (int i = 0; i < 8; ++i) {
      int u = kk * 32 + grp * 8 + i;
      float t = (vv[i] - muT[u]) * rsT[u];
      t = t > 0.f ? t : expm1f(t);
      af[i] = (__bf16)t;
    }
    bf16x8 bv = asbf(*(const int4*)(wrow + kk * 32));
    acc = __builtin_amdgcn_mfma_f32_16x16x32_bf16(af, bv, acc, 0, 0, 0);
  }
  const int col = w * 16 + c;
  const float mu = muR[col], rsv = rsR[col];
  float s = 0.f, q = 0.f;
#pragma unroll
  for (int r = 0; r < 4; ++r) {
    int row = r0 + grp * 4 + r;
    float v = acc[r] + (R[row * 64 + col] - mu) * rsv;
    S[row * 64 + col] = v;
    s += v; q = fmaf(v, v, q);
  }
  s += __shfl_xor(s, 16); s += __shfl_xor(s, 32);
  q += __shfl_xor(q, 16); q += __shfl_xor(q, 32);
  if (grp == 0) { PartS[blockIdx.x * 128 + col] = s; PartS[blockIdx.x * 128 + 64 + col] = q; }
}

// ---------------- K6: out = BN(S) ----------------
__global__ void __launch_bounds__(256) k6_bn(const float* __restrict__ S, const float* __restrict__ muS,
                                             const float* __restrict__ rsS, float* __restrict__ out) {
  int idx = blockIdx.x * 256 + threadIdx.x;     // 65536 float4s
  float4 v = ((const float4*)S)[idx];
  int f0 = (idx * 4) & 63;
  float4 o;
  o.x = (v.x - muS[f0])     * rsS[f0];
  o.y = (v.y - muS[f0 + 1]) * rsS[f0 + 1];
  o.z = (v.z - muS[f0 + 2]) * rsS[f0 + 2];
  o.w = (v.w - muS[f0 + 3]) * rsS[f0 + 3];
  ((float4*)out)[idx] = o;
}

extern "C" void kernel_launch(void* const* d_in, const int* in_sizes, int n_in,
                              void* d_out, int out_size, void* d_ws, size_t ws_size,
                              hipStream_t stream) {
  const int*   A      = (const int*)d_in[0];
  const float* X      = (const float*)d_in[1];
  const float* Ws     = (const float*)d_in[2];
  const float* a1     = (const float*)d_in[3];
  const float* a2     = (const float*)d_in[4];
  const float* W_emb1 = (const float*)d_in[5];
  const float* W2a    = (const float*)d_in[6];
  const float* W2b    = (const float*)d_in[7];
  float* out = (float*)d_out;

  float* ws = (float*)d_ws;
  // Workspace layout in FLOAT units. WhT is 128*64*512 ush = 2,097,152 floats (the
  // R2 bug gave it 262,144 -> k1 clobbered s1/s2/Xb/WsT... -> NaN). Fixed extents:
  ush*   Hb    = (ush*)d_ws;                 // [4096][1024] bf16      (2,097,152 fl)
  ush*   WhT   = (ush*)(ws + 2097152);       // [128][64][512] bf16    (2,097,152 fl)
  float* s1    = ws + 4194304;               // 65,536
  float* s2    = ws + 4259840;               // 65,536
  ush*   Xb    = (ush*)(ws + 4325376);       // [4096][64] bf16        (131,072 fl)
  ush*   WsT   = (ush*)(ws + 4456448);       // [16][64][64] bf16      (32,768 fl)
  ush*   cpack = (ush*)(ws + 4489216);       // [16][16][64] bf16      (8,192 fl)
  ush*   W1b   = (ush*)(ws + 4497408);       // [64][1024] bf16        (32,768 fl)
  ush*   W2ab  = (ush*)(ws + 4530176);       // [256][64] bf16         (8,192 fl)
  ush*   W2bb  = (ush*)(ws + 4538368);       // [64][256] bf16         (8,192 fl)
  float* stats = ws + 4546560;               // 768
  float* muR = stats,       *rsR = stats + 64;
  float* muT = stats + 128, *rsT = stats + 384;
  float* muS = stats + 640, *rsS = stats + 704;
  float* R     = ws + 4547328;               // 262,144
  float* T     = ws + 4809472;               // 1,048,576
  float* S     = ws + 5858048;               // 262,144
  float* PartR = ws + 6120192;               // 32,768
  float* PartT = ws + 6152960;               // 131,072
  float* PartS = ws + 6284032;               // 32,768  (end 6,316,800 fl ~ 25.3 MB)

  kprep<<<612, 256, 0, stream>>>(X, Ws, a1, a2, W_emb1, W2a, W2b, Xb, WsT, cpack, W1b, W2ab, W2bb);
  k1_wh<<<1024, 256, 0, stream>>>(Xb, WsT, cpack, WhT, s1, s2);
  k2_attn<<<1024, 256, 0, stream>>>(A, WhT, s1, s2, Hb);
  k3_emb<<<256, 256, 0, stream>>>(Hb, W1b, X, R, PartR);
  kstat<<<1, 256, 0, stream>>>(PartR, muR, rsR, 64);
  k4_node1<<<256, 256, 0, stream>>>(R, muR, rsR, W2ab, T, PartT);
  kstat<<<2, 256, 0, stream>>>(PartT, muT, rsT, 256);
  k5_node2<<<256, 256, 0, stream>>>(T, muT, rsT, W2bb, R, muR, rsR, S, PartS);
  kstat<<<1, 256, 0, stream>>>(PartS, muS, rsS, 64);
  k6_bn<<<256, 256, 0, stream>>>(S, muS, rsS, out);
}